// Round 9
// baseline (84.118 us; speedup 1.0000x reference)
//
#include <hip/hip_runtime.h>

// LinearAttention fp32 [4,16,4096,64]: out = (Q' (K'^T V)) / (Q'.k_sum + eps), X' = elu(X)+1.
// Pass 1 (kv_mfma): stage raw K,V into LDS via __builtin_amdgcn_global_load_lds
//   (16B/lane, no VGPR round-trip -> all loads outstanding, ONE latency exposure
//   per block), then LDS read-back -> elu -> bf16 pack/transpose IN PLACE ->
//   mfma_f32_16x16x32_bf16 (K=128). Partials -> ws (no atomics).
// Pass 1b (reduce_partials): fold NPB partials per bh.
// Pass 2 (out_kernel): unchanged.

#define EPS_LA 1e-6f

constexpr int BH = 64;
constexpr int SEQ = 4096;
constexpr int DIM = 64;
constexpr int KVELEM = DIM * DIM + DIM;  // 4160
constexpr int NPB = 32;                  // partial blocks per bh
constexpr int SCH = SEQ / NPB;           // 128 s-rows per block

typedef short bf16x8 __attribute__((ext_vector_type(8)));
typedef float f32x4 __attribute__((ext_vector_type(4)));

__device__ __forceinline__ float elu1(float x) {
    return x > 0.f ? x + 1.f : __expf(x);
}
__device__ __forceinline__ void elu4(float4& v) {
    v.x = elu1(v.x); v.y = elu1(v.y); v.z = elu1(v.z); v.w = elu1(v.w);
}

// fp32 -> bf16 (RNE; inputs finite)
__device__ __forceinline__ unsigned int f2bf(float x) {
    unsigned int u = __float_as_uint(x);
    return (u + 0x7fffu + ((u >> 16) & 1u)) >> 16;
}
__device__ __forceinline__ unsigned int pack2bf(float lo, float hi) {
    return f2bf(lo) | (f2bf(hi) << 16);
}

// Dword index into KT/VT[64 d-rows][64 s-pairs]; XOR into s2 bits 2..4 keeps 16B
// alignment; staging writes ~2-way, MFMA b128 reads near the b128 minimum.
__device__ __forceinline__ int swz(int d, int s2) {
    return d * 64 + (s2 ^ ((((d >> 1) ^ (d >> 2)) & 7) << 2));
}

// async global->LDS, 16B per lane; lds base must be wave-uniform (HW adds lane*16)
__device__ __forceinline__ void gload_lds16(const float* g, float* l) {
    __builtin_amdgcn_global_load_lds(
        (const __attribute__((address_space(1))) void*)g,
        (__attribute__((address_space(3))) void*)l,
        16, 0, 0);
}

template<bool ATOMIC>
__global__ __launch_bounds__(256, 4) void kv_mfma_kernel(
    const float* __restrict__ K, const float* __restrict__ V,
    float* __restrict__ dst) {
    const int bh = blockIdx.y;
    const int blk = blockIdx.x;
    const int t = threadIdx.x;
    const int w = t >> 6, l = t & 63;

    __shared__ float raw[2][SCH * DIM];  // 2 x 32 KB: raw K, raw V (then packed KT/VT)
    __shared__ float csumS[4][64];       // 1 KB

    const float* Kb = K + ((size_t)bh * SEQ + (size_t)blk * SCH) * DIM;
    const float* Vb = V + ((size_t)bh * SEQ + (size_t)blk * SCH) * DIM;

    // ---- stage: 32 chunks of 1KB each per array, all outstanding (no VGPRs) ----
    #pragma unroll
    for (int i = 0; i < 8; ++i) {
        const int c = w * 8 + i;  // chunk = 4 rows = 256 floats
        gload_lds16(Kb + c * 256 + l * 4, &raw[0][c * 256]);
    }
    #pragma unroll
    for (int i = 0; i < 8; ++i) {
        const int c = w * 8 + i;
        gload_lds16(Vb + c * 256 + l * 4, &raw[1][c * 256]);
    }
    __syncthreads();  // drains vmcnt(0): the single HBM-latency exposure

    // ---- read back per-thread pack slice (LDS-fast), hold across barrier ----
    const int c0 = (t & 15) * 4;  // d-col base
    const int pg = t >> 4;        // s-pair group base
    float4 kf[8], vf[8];
    #pragma unroll
    for (int i = 0; i < 4; ++i) {
        const int p = pg + 16 * i;
        kf[2 * i]     = *(const float4*)&raw[0][(size_t)(2 * p) * DIM + c0];
        kf[2 * i + 1] = *(const float4*)&raw[0][(size_t)(2 * p + 1) * DIM + c0];
        vf[2 * i]     = *(const float4*)&raw[1][(size_t)(2 * p) * DIM + c0];
        vf[2 * i + 1] = *(const float4*)&raw[1][(size_t)(2 * p + 1) * DIM + c0];
    }
    __syncthreads();  // all raw reads complete before in-place packed writes

    // ---- elu + pack + transpose (in place: packed is half the raw size) ----
    unsigned int* KT = (unsigned int*)&raw[0][0];
    unsigned int* VT = (unsigned int*)&raw[1][0];
    float cs0 = 0.f, cs1 = 0.f, cs2 = 0.f, cs3 = 0.f;
    #pragma unroll
    for (int i = 0; i < 4; ++i) {
        const int p = pg + 16 * i;
        float4 ka = kf[2 * i], kb = kf[2 * i + 1];
        elu4(ka); elu4(kb);
        cs0 += ka.x + kb.x; cs1 += ka.y + kb.y;
        cs2 += ka.z + kb.z; cs3 += ka.w + kb.w;
        KT[swz(c0 + 0, p)] = pack2bf(ka.x, kb.x);
        KT[swz(c0 + 1, p)] = pack2bf(ka.y, kb.y);
        KT[swz(c0 + 2, p)] = pack2bf(ka.z, kb.z);
        KT[swz(c0 + 3, p)] = pack2bf(ka.w, kb.w);
        const float4 va = vf[2 * i], vb = vf[2 * i + 1];
        VT[swz(c0 + 0, p)] = pack2bf(va.x, vb.x);
        VT[swz(c0 + 1, p)] = pack2bf(va.y, vb.y);
        VT[swz(c0 + 2, p)] = pack2bf(va.z, vb.z);
        VT[swz(c0 + 3, p)] = pack2bf(va.w, vb.w);
    }

    // fold column sums across 16-lane groups (lanes l, l^16, l^32, l^48 share c0)
    cs0 += __shfl_xor(cs0, 16); cs0 += __shfl_xor(cs0, 32);
    cs1 += __shfl_xor(cs1, 16); cs1 += __shfl_xor(cs1, 32);
    cs2 += __shfl_xor(cs2, 16); cs2 += __shfl_xor(cs2, 32);
    cs3 += __shfl_xor(cs3, 16); cs3 += __shfl_xor(cs3, 32);
    if (l < 16) *(float4*)&csumS[w][l * 4] = make_float4(cs0, cs1, cs2, cs3);

    __syncthreads();  // packed KT/VT + csumS visible

    // ---- MFMA: wave w owns e-cols [16w,16w+16); K=128 (4 steps of 32) ----
    const int lg = l >> 4;   // k-slice group 0..3
    const int lr = l & 15;   // row/col within tile
    f32x4 acc[4];
    #pragma unroll
    for (int m = 0; m < 4; ++m)
        #pragma unroll
        for (int r = 0; r < 4; ++r) acc[m][r] = 0.f;

    #pragma unroll
    for (int ks = 0; ks < 4; ++ks) {
        const int s2b = ks * 16 + lg * 4;  // 16B-aligned dword base of k-slice
        const bf16x8 bfrag =
            *reinterpret_cast<const bf16x8*>(&VT[swz(16 * w + lr, s2b)]);
        #pragma unroll
        for (int m = 0; m < 4; ++m) {
            const bf16x8 afrag =
                *reinterpret_cast<const bf16x8*>(&KT[swz(16 * m + lr, s2b)]);
            acc[m] = __builtin_amdgcn_mfma_f32_16x16x32_bf16(afrag, bfrag, acc[m],
                                                             0, 0, 0);
        }
    }

    float* wout = ATOMIC ? dst + (size_t)bh * KVELEM
                         : dst + ((size_t)blk * BH + bh) * KVELEM;

    // ksum: fold the 4 wave partials
    if (t < 64) {
        const float s = csumS[0][t] + csumS[1][t] + csumS[2][t] + csumS[3][t];
        if (ATOMIC) atomicAdd(&wout[DIM * DIM + t], s);
        else        wout[DIM * DIM + t] = s;
    }

    // store D: tile m -> rows d=16m+4lg+r, col e=16w+lr
    #pragma unroll
    for (int m = 0; m < 4; ++m) {
        #pragma unroll
        for (int r = 0; r < 4; ++r) {
            const int d = 16 * m + 4 * lg + r;
            const int e = 16 * w + lr;
            if (ATOMIC) atomicAdd(&wout[(size_t)d * DIM + e], acc[m][r]);
            else        wout[(size_t)d * DIM + e] = acc[m][r];
        }
    }
}

__global__ __launch_bounds__(256) void reduce_partials_kernel(
    const float* __restrict__ partial, float* __restrict__ fin) {
    const int bh = blockIdx.y;
    const int j = blockIdx.x * 256 + threadIdx.x;
    if (j >= KVELEM) return;
    float s = 0.f;
    #pragma unroll
    for (int c = 0; c < NPB; ++c)
        s += partial[((size_t)c * BH + bh) * KVELEM + j];
    fin[(size_t)bh * KVELEM + j] = s;
}

// Pass 2: block = 256 thr (4 waves), 128 q-rows/block (32/wave). Thread tile 4x8.
__global__ __launch_bounds__(256) void out_kernel(
    const float* __restrict__ Q, const float* __restrict__ ws,
    float* __restrict__ out) {
    const int bh = blockIdx.y;
    const int rb = blockIdx.x;  // 128-row block
    const int wave = threadIdx.x >> 6, lane = threadIdx.x & 63;
    const int t = threadIdx.x;
    const int tr = lane >> 3;   // 0..7 -> rows 4tr..4tr+3 (within wave's 32)
    const int tc = lane & 7;    // 0..7 -> cols 8tc..8tc+7

    const float* w = ws + (size_t)bh * KVELEM;
    const float* Qw = Q + ((size_t)bh * SEQ + (size_t)rb * 128 + (size_t)wave * 32) * DIM;
    float* Ow = out + ((size_t)bh * SEQ + (size_t)rb * 128 + (size_t)wave * 32) * DIM;

    __shared__ float kvS[DIM][DIM];    // 16 KB
    __shared__ float ksumS[DIM];
    __shared__ float qS[4][32][DIM];   // 32 KB, per-wave, XOR-swizzled col-chunks

    // cooperative kv load (whole block, 4096 floats)
    #pragma unroll
    for (int i = 0; i < 4; ++i) {
        const int idx = (i * 256 + t) * 4;
        *(float4*)&kvS[idx >> 6][idx & 63] = *(const float4*)(w + idx);
    }
    if (t < DIM) ksumS[t] = w[DIM * DIM + t];

    // per-wave q stage: 32 rows x 64 cols, elu'd; col-chunk cc stored at cc^((row>>2)&7)
    #pragma unroll
    for (int it = 0; it < 8; ++it) {
        const int row = it * 4 + (lane >> 4);   // 0..31
        const int cc = lane & 15;               // col chunk 0..15
        float4 qv = *(const float4*)(Qw + (size_t)row * DIM + cc * 4);
        elu4(qv);
        *(float4*)&qS[wave][row][((cc ^ ((row >> 2) & 7)) & 15) * 4] = qv;
    }
    __syncthreads();

    float acc[4][8] = {{0.f}};
    float accd[4] = {0.f, 0.f, 0.f, 0.f};

    #pragma unroll 2
    for (int dc = 0; dc < 16; ++dc) {  // d-chunks of 4
        float4 qv[4];
        #pragma unroll
        for (int i = 0; i < 4; ++i)
            qv[i] = *(const float4*)&qS[wave][tr * 4 + i][((dc ^ tr) & 15) * 4];
        const float4 ks = *(const float4*)&ksumS[dc * 4];
        #pragma unroll
        for (int dd = 0; dd < 4; ++dd) {
            const int d = dc * 4 + dd;
            const float4 ka = *(const float4*)&kvS[d][tc * 8];
            const float4 kb = *(const float4*)&kvS[d][tc * 8 + 4];
            const float ksd = (&ks.x)[dd];
            #pragma unroll
            for (int i = 0; i < 4; ++i) {
                const float qq = (&qv[i].x)[dd];
                accd[i] += qq * ksd;
                acc[i][0] += qq * ka.x; acc[i][1] += qq * ka.y;
                acc[i][2] += qq * ka.z; acc[i][3] += qq * ka.w;
                acc[i][4] += qq * kb.x; acc[i][5] += qq * kb.y;
                acc[i][6] += qq * kb.z; acc[i][7] += qq * kb.w;
            }
        }
    }

    #pragma unroll
    for (int i = 0; i < 4; ++i) {
        const float inv = 1.f / (accd[i] + EPS_LA);
        float4 o0, o1;
        o0.x = acc[i][0] * inv; o0.y = acc[i][1] * inv;
        o0.z = acc[i][2] * inv; o0.w = acc[i][3] * inv;
        o1.x = acc[i][4] * inv; o1.y = acc[i][5] * inv;
        o1.z = acc[i][6] * inv; o1.w = acc[i][7] * inv;
        float* orow = Ow + (size_t)(tr * 4 + i) * DIM + tc * 8;
        *(float4*)(orow) = o0;
        *(float4*)(orow + 4) = o1;
    }
}

extern "C" void kernel_launch(void* const* d_in, const int* in_sizes, int n_in,
                              void* d_out, int out_size, void* d_ws, size_t ws_size,
                              hipStream_t stream) {
    const float* q = (const float*)d_in[0];
    const float* k = (const float*)d_in[1];
    const float* v = (const float*)d_in[2];
    float* out = (float*)d_out;
    float* ws = (float*)d_ws;

    const size_t partial_elems = (size_t)NPB * BH * KVELEM;
    const size_t need = (partial_elems + (size_t)BH * KVELEM) * sizeof(float);

    dim3 blk(256);
    const float* fin_ptr;
    if (ws_size >= need) {
        float* partial = ws;
        float* fin = ws + partial_elems;
        hipLaunchKernelGGL((kv_mfma_kernel<false>), dim3(NPB, BH), blk, 0, stream,
                           k, v, partial);
        hipLaunchKernelGGL(reduce_partials_kernel, dim3((KVELEM + 255) / 256, BH),
                           blk, 0, stream, partial, fin);
        fin_ptr = fin;
    } else {
        float* fin = ws;
        hipMemsetAsync(fin, 0, (size_t)BH * KVELEM * sizeof(float), stream);
        hipLaunchKernelGGL((kv_mfma_kernel<true>), dim3(NPB, BH), blk, 0, stream,
                           k, v, fin);
        fin_ptr = fin;
    }
    hipLaunchKernelGGL(out_kernel, dim3(SEQ / 128, BH), blk, 0, stream,
                       q, fin_ptr, out);
}

// Round 10
// 79.203 us; speedup vs baseline: 1.0621x; 1.0621x over previous
//
#include <hip/hip_runtime.h>

// LinearAttention fp32 [4,16,4096,64]: out = (Q' (K'^T V)) / (Q'.k_sum + eps), X' = elu(X)+1.
// R10: NON-TEMPORAL streaming for all single-touch data (K,V,Q reads, out writes).
//   Working set (~300MB) exceeds the 256MB L3 -> mixed hit/miss churn was serving
//   HBM at only 1.3 TB/s (Swiss-cheese misses). NT loads bypass cache pollution;
//   L3 is reserved for the partials/kv aggregate (35MB, fully resident).
// Pass 1 (kv_mfma): single-phase: 16 NT float4 loads -> elu/pack bf16 transposed
//   into LDS (conflict-free XOR swizzle) -> one barrier -> 16x mfma 16x16x32_bf16.
// Pass 1b (reduce_partials): fold NPB partials per bh (L3-resident).
// Pass 2 (out_kernel): NT Q loads, NT out stores; kv/ksum from L3.

#define EPS_LA 1e-6f

constexpr int BH = 64;
constexpr int SEQ = 4096;
constexpr int DIM = 64;
constexpr int KVELEM = DIM * DIM + DIM;  // 4160
constexpr int NPB = 32;                  // partial blocks per bh
constexpr int SCH = SEQ / NPB;           // 128 s-rows per block

typedef short bf16x8 __attribute__((ext_vector_type(8)));
typedef float f32x4 __attribute__((ext_vector_type(4)));

__device__ __forceinline__ float elu1(float x) {
    return x > 0.f ? x + 1.f : __expf(x);
}
__device__ __forceinline__ f32x4 elu4v(f32x4 v) {
    v[0] = elu1(v[0]); v[1] = elu1(v[1]); v[2] = elu1(v[2]); v[3] = elu1(v[3]);
    return v;
}
// non-temporal 16B load/store (gfx950 'nt' cache policy — no L2/L3 pollution)
__device__ __forceinline__ f32x4 ntld(const float* p) {
    return __builtin_nontemporal_load((const f32x4*)p);
}
__device__ __forceinline__ void ntst(float* p, f32x4 v) {
    __builtin_nontemporal_store(v, (f32x4*)p);
}

// fp32 -> bf16 (RNE; inputs finite)
__device__ __forceinline__ unsigned int f2bf(float x) {
    unsigned int u = __float_as_uint(x);
    return (u + 0x7fffu + ((u >> 16) & 1u)) >> 16;
}
__device__ __forceinline__ unsigned int pack2bf(float lo, float hi) {
    return f2bf(lo) | (f2bf(hi) << 16);
}

// Dword index into KT/VT[64 d-rows][64 s-pairs]. XOR into s2 bits 2..4 keeps 16B
// alignment; staging writes ~2-way (free), MFMA b128 reads near the b128 minimum.
__device__ __forceinline__ int swz(int d, int s2) {
    return d * 64 + (s2 ^ ((((d >> 1) ^ (d >> 2)) & 7) << 2));
}

template<bool ATOMIC>
__global__ __launch_bounds__(256, 2) void kv_mfma_kernel(
    const float* __restrict__ K, const float* __restrict__ V,
    float* __restrict__ dst) {
    const int bh = blockIdx.y;
    const int blk = blockIdx.x;
    const int t = threadIdx.x;
    const int w = t >> 6, l = t & 63;

    __shared__ unsigned int KT[64 * 64];  // 16 KB: K'^T bf16 [d][s-pair] swizzled
    __shared__ unsigned int VT[64 * 64];  // 16 KB
    __shared__ float csumS[4][64];        // 1 KB

    const float* Kb = K + ((size_t)bh * SEQ + (size_t)blk * SCH) * DIM;
    const float* Vb = V + ((size_t)bh * SEQ + (size_t)blk * SCH) * DIM;

    const int c0 = (t & 15) * 4;  // staged col base (d rows c0..c0+3)
    const int pg = t >> 4;        // s-pair group base: pairs pg, pg+16, pg+32, pg+48
    const int lg = l >> 4;        // MFMA k-slice group 0..3
    const int lr = l & 15;        // MFMA row/col within tile

    // ---- issue ALL 16 non-temporal loads (kept in registers; (256,2) => room) ----
    f32x4 kf[8], vf[8];
    #pragma unroll
    for (int i = 0; i < 4; ++i) {
        const int p = pg + 16 * i;
        kf[2 * i]     = ntld(Kb + (size_t)(2 * p) * DIM + c0);
        kf[2 * i + 1] = ntld(Kb + (size_t)(2 * p + 1) * DIM + c0);
    }
    #pragma unroll
    for (int i = 0; i < 4; ++i) {
        const int p = pg + 16 * i;
        vf[2 * i]     = ntld(Vb + (size_t)(2 * p) * DIM + c0);
        vf[2 * i + 1] = ntld(Vb + (size_t)(2 * p + 1) * DIM + c0);
    }

    // ---- elu + pack + transpose into LDS ----
    float cs0 = 0.f, cs1 = 0.f, cs2 = 0.f, cs3 = 0.f;
    #pragma unroll
    for (int i = 0; i < 4; ++i) {
        const int p = pg + 16 * i;
        const f32x4 ka = elu4v(kf[2 * i]);
        const f32x4 kb = elu4v(kf[2 * i + 1]);
        cs0 += ka[0] + kb[0]; cs1 += ka[1] + kb[1];
        cs2 += ka[2] + kb[2]; cs3 += ka[3] + kb[3];
        KT[swz(c0 + 0, p)] = pack2bf(ka[0], kb[0]);
        KT[swz(c0 + 1, p)] = pack2bf(ka[1], kb[1]);
        KT[swz(c0 + 2, p)] = pack2bf(ka[2], kb[2]);
        KT[swz(c0 + 3, p)] = pack2bf(ka[3], kb[3]);
        const f32x4 va = vf[2 * i], vb = vf[2 * i + 1];
        VT[swz(c0 + 0, p)] = pack2bf(va[0], vb[0]);
        VT[swz(c0 + 1, p)] = pack2bf(va[1], vb[1]);
        VT[swz(c0 + 2, p)] = pack2bf(va[2], vb[2]);
        VT[swz(c0 + 3, p)] = pack2bf(va[3], vb[3]);
    }

    // fold column sums across 16-lane groups (lanes l, l^16, l^32, l^48 share c0)
    cs0 += __shfl_xor(cs0, 16); cs0 += __shfl_xor(cs0, 32);
    cs1 += __shfl_xor(cs1, 16); cs1 += __shfl_xor(cs1, 32);
    cs2 += __shfl_xor(cs2, 16); cs2 += __shfl_xor(cs2, 32);
    cs3 += __shfl_xor(cs3, 16); cs3 += __shfl_xor(cs3, 32);
    if (l < 16) *(f32x4*)&csumS[w][l * 4] = f32x4{cs0, cs1, cs2, cs3};

    __syncthreads();  // the ONLY barrier

    // ---- MFMA: wave w owns e-cols [16w,16w+16); K=128 (4 steps of 32) ----
    f32x4 acc[4];
    #pragma unroll
    for (int m = 0; m < 4; ++m)
        #pragma unroll
        for (int r = 0; r < 4; ++r) acc[m][r] = 0.f;

    #pragma unroll
    for (int ks = 0; ks < 4; ++ks) {
        const int s2b = ks * 16 + lg * 4;  // 16B-aligned dword base of k-slice
        const bf16x8 bfrag =
            *reinterpret_cast<const bf16x8*>(&VT[swz(16 * w + lr, s2b)]);
        #pragma unroll
        for (int m = 0; m < 4; ++m) {
            const bf16x8 afrag =
                *reinterpret_cast<const bf16x8*>(&KT[swz(16 * m + lr, s2b)]);
            acc[m] = __builtin_amdgcn_mfma_f32_16x16x32_bf16(afrag, bfrag, acc[m],
                                                             0, 0, 0);
        }
    }

    float* wout = ATOMIC ? dst + (size_t)bh * KVELEM
                         : dst + ((size_t)blk * BH + bh) * KVELEM;

    // ksum: fold the 4 wave partials (visible since the barrier)
    if (t < 64) {
        const float s = csumS[0][t] + csumS[1][t] + csumS[2][t] + csumS[3][t];
        if (ATOMIC) atomicAdd(&wout[DIM * DIM + t], s);
        else        wout[DIM * DIM + t] = s;
    }

    // store D (partials: L3-resident on purpose — reduce reads them right away)
    #pragma unroll
    for (int m = 0; m < 4; ++m) {
        #pragma unroll
        for (int r = 0; r < 4; ++r) {
            const int d = 16 * m + 4 * lg + r;
            const int e = 16 * w + lr;
            if (ATOMIC) atomicAdd(&wout[(size_t)d * DIM + e], acc[m][r]);
            else        wout[(size_t)d * DIM + e] = acc[m][r];
        }
    }
}

__global__ __launch_bounds__(256) void reduce_partials_kernel(
    const float* __restrict__ partial, float* __restrict__ fin) {
    const int bh = blockIdx.y;
    const int j = blockIdx.x * 256 + threadIdx.x;
    if (j >= KVELEM) return;
    float s = 0.f;
    #pragma unroll
    for (int c = 0; c < NPB; ++c)
        s += partial[((size_t)c * BH + bh) * KVELEM + j];
    fin[(size_t)bh * KVELEM + j] = s;
}

// Pass 2: block = 256 thr (4 waves), 128 q-rows/block (32/wave). Thread tile 4x8.
// NT for the Q stream and out stream; kv/ksum (L3-hot) via normal loads.
__global__ __launch_bounds__(256) void out_kernel(
    const float* __restrict__ Q, const float* __restrict__ ws,
    float* __restrict__ out) {
    const int bh = blockIdx.y;
    const int rb = blockIdx.x;  // 128-row block
    const int wave = threadIdx.x >> 6, lane = threadIdx.x & 63;
    const int t = threadIdx.x;
    const int tr = lane >> 3;   // 0..7 -> rows 4tr..4tr+3 (within wave's 32)
    const int tc = lane & 7;    // 0..7 -> cols 8tc..8tc+7

    const float* w = ws + (size_t)bh * KVELEM;
    const float* Qw = Q + ((size_t)bh * SEQ + (size_t)rb * 128 + (size_t)wave * 32) * DIM;
    float* Ow = out + ((size_t)bh * SEQ + (size_t)rb * 128 + (size_t)wave * 32) * DIM;

    __shared__ float kvS[DIM][DIM];    // 16 KB
    __shared__ float ksumS[DIM];
    __shared__ float qS[4][32][DIM];   // 32 KB, per-wave, XOR-swizzled col-chunks

    // cooperative kv load (whole block, 4096 floats; L3-resident)
    #pragma unroll
    for (int i = 0; i < 4; ++i) {
        const int idx = (i * 256 + t) * 4;
        *(f32x4*)&kvS[idx >> 6][idx & 63] = *(const f32x4*)(w + idx);
    }
    if (t < DIM) ksumS[t] = w[DIM * DIM + t];

    // per-wave q stage (NT): 32 rows x 64 cols, elu'd; col-chunk cc at cc^((row>>2)&7)
    #pragma unroll
    for (int it = 0; it < 8; ++it) {
        const int row = it * 4 + (lane >> 4);   // 0..31
        const int cc = lane & 15;               // col chunk 0..15
        const f32x4 qv = elu4v(ntld(Qw + (size_t)row * DIM + cc * 4));
        *(f32x4*)&qS[wave][row][((cc ^ ((row >> 2) & 7)) & 15) * 4] = qv;
    }
    __syncthreads();

    float acc[4][8] = {{0.f}};
    float accd[4] = {0.f, 0.f, 0.f, 0.f};

    #pragma unroll 2
    for (int dc = 0; dc < 16; ++dc) {  // d-chunks of 4
        f32x4 qv[4];
        #pragma unroll
        for (int i = 0; i < 4; ++i)
            qv[i] = *(const f32x4*)&qS[wave][tr * 4 + i][((dc ^ tr) & 15) * 4];
        const f32x4 ks = *(const f32x4*)&ksumS[dc * 4];
        #pragma unroll
        for (int dd = 0; dd < 4; ++dd) {
            const int d = dc * 4 + dd;
            const f32x4 ka = *(const f32x4*)&kvS[d][tc * 8];
            const f32x4 kb = *(const f32x4*)&kvS[d][tc * 8 + 4];
            const float ksd = ks[dd];
            #pragma unroll
            for (int i = 0; i < 4; ++i) {
                const float qq = qv[i][dd];
                accd[i] += qq * ksd;
                acc[i][0] += qq * ka[0]; acc[i][1] += qq * ka[1];
                acc[i][2] += qq * ka[2]; acc[i][3] += qq * ka[3];
                acc[i][4] += qq * kb[0]; acc[i][5] += qq * kb[1];
                acc[i][6] += qq * kb[2]; acc[i][7] += qq * kb[3];
            }
        }
    }

    #pragma unroll
    for (int i = 0; i < 4; ++i) {
        const float inv = 1.f / (accd[i] + EPS_LA);
        f32x4 o0, o1;
        o0[0] = acc[i][0] * inv; o0[1] = acc[i][1] * inv;
        o0[2] = acc[i][2] * inv; o0[3] = acc[i][3] * inv;
        o1[0] = acc[i][4] * inv; o1[1] = acc[i][5] * inv;
        o1[2] = acc[i][6] * inv; o1[3] = acc[i][7] * inv;
        float* orow = Ow + (size_t)(tr * 4 + i) * DIM + tc * 8;
        ntst(orow, o0);
        ntst(orow + 4, o1);
    }
}

extern "C" void kernel_launch(void* const* d_in, const int* in_sizes, int n_in,
                              void* d_out, int out_size, void* d_ws, size_t ws_size,
                              hipStream_t stream) {
    const float* q = (const float*)d_in[0];
    const float* k = (const float*)d_in[1];
    const float* v = (const float*)d_in[2];
    float* out = (float*)d_out;
    float* ws = (float*)d_ws;

    const size_t partial_elems = (size_t)NPB * BH * KVELEM;
    const size_t need = (partial_elems + (size_t)BH * KVELEM) * sizeof(float);

    dim3 blk(256);
    const float* fin_ptr;
    if (ws_size >= need) {
        float* partial = ws;
        float* fin = ws + partial_elems;
        hipLaunchKernelGGL((kv_mfma_kernel<false>), dim3(NPB, BH), blk, 0, stream,
                           k, v, partial);
        hipLaunchKernelGGL(reduce_partials_kernel, dim3((KVELEM + 255) / 256, BH),
                           blk, 0, stream, partial, fin);
        fin_ptr = fin;
    } else {
        float* fin = ws;
        hipMemsetAsync(fin, 0, (size_t)BH * KVELEM * sizeof(float), stream);
        hipLaunchKernelGGL((kv_mfma_kernel<true>), dim3(NPB, BH), blk, 0, stream,
                           k, v, fin);
        fin_ptr = fin;
    }
    hipLaunchKernelGGL(out_kernel, dim3(SEQ / 128, BH), blk, 0, stream,
                       q, fin_ptr, out);
}

// Round 11
// 69.738 us; speedup vs baseline: 1.2062x; 1.1357x over previous
//
#include <hip/hip_runtime.h>

// LinearAttention fp32 [4,16,4096,64]: out = (Q' (K'^T V)) / (Q'.k_sum + eps), X' = elu(X)+1.
// R11: pass 2 moved to MFMA (it was VALU-bound at 57% VALUBusy / 43us).
// Pass 1 (kv_mfma): unchanged from R10 — NT loads, single-phase, bf16 MFMA.
// Pass 1b (reduce_partials): unchanged.
// Pass 2 (out_kernel): per-wave 32 q-rows: Q' bf16-packed + kv^T bf16 in LDS
//   (pass-1-verified swizzle/fragment geometry), 20x mfma_f32_16x16x32_bf16;
//   denom kept FP32 (per-thread dot + shfl butterfly) for accuracy; NT Q loads,
//   NT out stores. LDS 25KB -> 6 blocks/CU.

#define EPS_LA 1e-6f

constexpr int BH = 64;
constexpr int SEQ = 4096;
constexpr int DIM = 64;
constexpr int KVELEM = DIM * DIM + DIM;  // 4160
constexpr int NPB = 32;                  // partial blocks per bh
constexpr int SCH = SEQ / NPB;           // 128 s-rows per block

typedef short bf16x8 __attribute__((ext_vector_type(8)));
typedef float f32x4 __attribute__((ext_vector_type(4)));

__device__ __forceinline__ float elu1(float x) {
    return x > 0.f ? x + 1.f : __expf(x);
}
__device__ __forceinline__ f32x4 elu4v(f32x4 v) {
    v[0] = elu1(v[0]); v[1] = elu1(v[1]); v[2] = elu1(v[2]); v[3] = elu1(v[3]);
    return v;
}
__device__ __forceinline__ f32x4 ntld(const float* p) {
    return __builtin_nontemporal_load((const f32x4*)p);
}

// fp32 -> bf16 (RNE; inputs finite)
__device__ __forceinline__ unsigned int f2bf(float x) {
    unsigned int u = __float_as_uint(x);
    return (u + 0x7fffu + ((u >> 16) & 1u)) >> 16;
}
__device__ __forceinline__ unsigned int pack2bf(float lo, float hi) {
    return f2bf(lo) | (f2bf(hi) << 16);
}

// Pass-1 LDS swizzle: dword index into [64 rows][64 dword-cols]
__device__ __forceinline__ int swz(int d, int s2) {
    return d * 64 + (s2 ^ ((((d >> 1) ^ (d >> 2)) & 7) << 2));
}

template<bool ATOMIC>
__global__ __launch_bounds__(256, 2) void kv_mfma_kernel(
    const float* __restrict__ K, const float* __restrict__ V,
    float* __restrict__ dst) {
    const int bh = blockIdx.y;
    const int blk = blockIdx.x;
    const int t = threadIdx.x;
    const int w = t >> 6, l = t & 63;

    __shared__ unsigned int KT[64 * 64];  // 16 KB: K'^T bf16 [d][s-pair] swizzled
    __shared__ unsigned int VT[64 * 64];  // 16 KB
    __shared__ float csumS[4][64];        // 1 KB

    const float* Kb = K + ((size_t)bh * SEQ + (size_t)blk * SCH) * DIM;
    const float* Vb = V + ((size_t)bh * SEQ + (size_t)blk * SCH) * DIM;

    const int c0 = (t & 15) * 4;  // staged col base (d rows c0..c0+3)
    const int pg = t >> 4;        // s-pair group base: pairs pg, pg+16, pg+32, pg+48
    const int lg = l >> 4;        // MFMA k-slice group 0..3
    const int lr = l & 15;        // MFMA row/col within tile

    // ---- issue ALL 16 non-temporal loads ----
    f32x4 kf[8], vf[8];
    #pragma unroll
    for (int i = 0; i < 4; ++i) {
        const int p = pg + 16 * i;
        kf[2 * i]     = ntld(Kb + (size_t)(2 * p) * DIM + c0);
        kf[2 * i + 1] = ntld(Kb + (size_t)(2 * p + 1) * DIM + c0);
    }
    #pragma unroll
    for (int i = 0; i < 4; ++i) {
        const int p = pg + 16 * i;
        vf[2 * i]     = ntld(Vb + (size_t)(2 * p) * DIM + c0);
        vf[2 * i + 1] = ntld(Vb + (size_t)(2 * p + 1) * DIM + c0);
    }

    // ---- elu + pack + transpose into LDS ----
    float cs0 = 0.f, cs1 = 0.f, cs2 = 0.f, cs3 = 0.f;
    #pragma unroll
    for (int i = 0; i < 4; ++i) {
        const int p = pg + 16 * i;
        const f32x4 ka = elu4v(kf[2 * i]);
        const f32x4 kb = elu4v(kf[2 * i + 1]);
        cs0 += ka[0] + kb[0]; cs1 += ka[1] + kb[1];
        cs2 += ka[2] + kb[2]; cs3 += ka[3] + kb[3];
        KT[swz(c0 + 0, p)] = pack2bf(ka[0], kb[0]);
        KT[swz(c0 + 1, p)] = pack2bf(ka[1], kb[1]);
        KT[swz(c0 + 2, p)] = pack2bf(ka[2], kb[2]);
        KT[swz(c0 + 3, p)] = pack2bf(ka[3], kb[3]);
        const f32x4 va = vf[2 * i], vb = vf[2 * i + 1];
        VT[swz(c0 + 0, p)] = pack2bf(va[0], vb[0]);
        VT[swz(c0 + 1, p)] = pack2bf(va[1], vb[1]);
        VT[swz(c0 + 2, p)] = pack2bf(va[2], vb[2]);
        VT[swz(c0 + 3, p)] = pack2bf(va[3], vb[3]);
    }

    // fold column sums across 16-lane groups
    cs0 += __shfl_xor(cs0, 16); cs0 += __shfl_xor(cs0, 32);
    cs1 += __shfl_xor(cs1, 16); cs1 += __shfl_xor(cs1, 32);
    cs2 += __shfl_xor(cs2, 16); cs2 += __shfl_xor(cs2, 32);
    cs3 += __shfl_xor(cs3, 16); cs3 += __shfl_xor(cs3, 32);
    if (l < 16) *(f32x4*)&csumS[w][l * 4] = f32x4{cs0, cs1, cs2, cs3};

    __syncthreads();  // the ONLY barrier

    // ---- MFMA: wave w owns e-cols [16w,16w+16); K=128 (4 steps of 32) ----
    f32x4 acc[4];
    #pragma unroll
    for (int m = 0; m < 4; ++m)
        #pragma unroll
        for (int r = 0; r < 4; ++r) acc[m][r] = 0.f;

    #pragma unroll
    for (int ks = 0; ks < 4; ++ks) {
        const int s2b = ks * 16 + lg * 4;
        const bf16x8 bfrag =
            *reinterpret_cast<const bf16x8*>(&VT[swz(16 * w + lr, s2b)]);
        #pragma unroll
        for (int m = 0; m < 4; ++m) {
            const bf16x8 afrag =
                *reinterpret_cast<const bf16x8*>(&KT[swz(16 * m + lr, s2b)]);
            acc[m] = __builtin_amdgcn_mfma_f32_16x16x32_bf16(afrag, bfrag, acc[m],
                                                             0, 0, 0);
        }
    }

    float* wout = ATOMIC ? dst + (size_t)bh * KVELEM
                         : dst + ((size_t)blk * BH + bh) * KVELEM;

    if (t < 64) {
        const float s = csumS[0][t] + csumS[1][t] + csumS[2][t] + csumS[3][t];
        if (ATOMIC) atomicAdd(&wout[DIM * DIM + t], s);
        else        wout[DIM * DIM + t] = s;
    }

    #pragma unroll
    for (int m = 0; m < 4; ++m) {
        #pragma unroll
        for (int r = 0; r < 4; ++r) {
            const int d = 16 * m + 4 * lg + r;
            const int e = 16 * w + lr;
            if (ATOMIC) atomicAdd(&wout[(size_t)d * DIM + e], acc[m][r]);
            else        wout[(size_t)d * DIM + e] = acc[m][r];
        }
    }
}

__global__ __launch_bounds__(256) void reduce_partials_kernel(
    const float* __restrict__ partial, float* __restrict__ fin) {
    const int bh = blockIdx.y;
    const int j = blockIdx.x * 256 + threadIdx.x;
    if (j >= KVELEM) return;
    float s = 0.f;
    #pragma unroll
    for (int c = 0; c < NPB; ++c)
        s += partial[((size_t)c * BH + bh) * KVELEM + j];
    fin[(size_t)bh * KVELEM + j] = s;
}

// Pass 2 (MFMA): block = 256 thr (4 waves); wave wv owns 32 q-rows. Per wave:
// 2 m-tiles x 4 n-tiles x 2 k-steps = 16 MFMA. Denom fp32 via shfl butterfly.
__global__ __launch_bounds__(256) void out_kernel(
    const float* __restrict__ Q, const float* __restrict__ ws,
    float* __restrict__ out) {
    const int bh = blockIdx.y;
    const int rb = blockIdx.x;  // 128-row block
    const int t = threadIdx.x;
    const int wv = t >> 6, l = t & 63;
    const int lr = l & 15, lg = l >> 4;

    __shared__ unsigned int qA[4 * 32 * 32];  // 16 KB: per-wave Q' bf16 [row][d-pair]
    __shared__ unsigned int kvT[64 * 32];     // 8 KB: kv^T bf16 [e][d-pair]
    __shared__ float denomS[128];

    const float* kvp = ws + (size_t)bh * KVELEM;
    const float* Qb = Q + ((size_t)bh * SEQ + (size_t)rb * 128) * DIM;
    float* Ob = out + ((size_t)bh * SEQ + (size_t)rb * 128) * DIM;

    // ---- kvT staging: kv[d][e] -> kvT[e][d-pairs] bf16, swizzled by (e&7) ----
    #pragma unroll
    for (int i = 0; i < 2; ++i) {
        const int p = (t >> 4) + 16 * i;     // d-pair 0..31
        const int e0 = (t & 15) * 4;
        const f32x4 a = *(const f32x4*)(kvp + (size_t)(2 * p) * DIM + e0);
        const f32x4 b = *(const f32x4*)(kvp + (size_t)(2 * p + 1) * DIM + e0);
        #pragma unroll
        for (int j = 0; j < 4; ++j) {
            const int e = e0 + j;
            kvT[e * 32 + (p ^ ((e & 7) << 2))] = pack2bf(a[j], b[j]);
        }
    }

    // ---- q staging (NT): elu, pack bf16, swizzle; fp32 denom partials ----
    const int c0 = lr * 4;
    const f32x4 ks4 = *(const f32x4*)(kvp + DIM * DIM + c0);  // fp32 ksum slice (hot)
    float pd[8];
    #pragma unroll
    for (int it = 0; it < 8; ++it) {
        const int row = it * 4 + lg;          // 0..31 within wave
        const f32x4 qv = elu4v(ntld(Qb + (size_t)(wv * 32 + row) * DIM + c0));
        pd[it] = qv[0] * ks4[0] + qv[1] * ks4[1] + qv[2] * ks4[2] + qv[3] * ks4[3];
        uint2 val;
        val.x = pack2bf(qv[0], qv[1]);
        val.y = pack2bf(qv[2], qv[3]);
        *(uint2*)&qA[wv * 1024 + row * 32 + ((2 * lr) ^ ((row & 7) << 2))] = val;
    }
    // butterfly over the 16-lane (lr) group -> full denom per row
    #pragma unroll
    for (int it = 0; it < 8; ++it) {
        float v = pd[it];
        v += __shfl_xor(v, 1); v += __shfl_xor(v, 2);
        v += __shfl_xor(v, 4); v += __shfl_xor(v, 8);
        if (lr == 0) denomS[wv * 32 + it * 4 + lg] = v + EPS_LA;
    }
    __syncthreads();

    // ---- MFMA: rows 16*mt+lr, cols 16*nt+lr, K=64 in 2 steps ----
    f32x4 acc[2][4];
    #pragma unroll
    for (int mt = 0; mt < 2; ++mt)
        #pragma unroll
        for (int nt = 0; nt < 4; ++nt)
            #pragma unroll
            for (int r = 0; r < 4; ++r) acc[mt][nt][r] = 0.f;

    #pragma unroll
    for (int ks = 0; ks < 2; ++ks) {
        const int kd = 4 * lg + 16 * ks;      // dword base of the lane's k-slice
        const int am = (lr & 7) << 2;
        const bf16x8 a0 = *(const bf16x8*)&qA[wv * 1024 + lr * 32 + (kd ^ am)];
        const bf16x8 a1 = *(const bf16x8*)&qA[wv * 1024 + (16 + lr) * 32 + (kd ^ am)];
        #pragma unroll
        for (int nt = 0; nt < 4; ++nt) {
            const bf16x8 b =
                *(const bf16x8*)&kvT[(16 * nt + lr) * 32 + (kd ^ am)];
            acc[0][nt] = __builtin_amdgcn_mfma_f32_16x16x32_bf16(a0, b, acc[0][nt],
                                                                 0, 0, 0);
            acc[1][nt] = __builtin_amdgcn_mfma_f32_16x16x32_bf16(a1, b, acc[1][nt],
                                                                 0, 0, 0);
        }
    }

    // ---- normalize + NT store: lane holds col 16*nt+lr, rows 16*mt+4*lg+r ----
    #pragma unroll
    for (int mt = 0; mt < 2; ++mt) {
        #pragma unroll
        for (int r = 0; r < 4; ++r) {
            const int row = 16 * mt + 4 * lg + r;
            const float inv = 1.f / denomS[wv * 32 + row];
            float* orow = Ob + (size_t)(wv * 32 + row) * DIM;
            #pragma unroll
            for (int nt = 0; nt < 4; ++nt) {
                __builtin_nontemporal_store(acc[mt][nt][r] * inv,
                                            orow + 16 * nt + lr);
            }
        }
    }
}

extern "C" void kernel_launch(void* const* d_in, const int* in_sizes, int n_in,
                              void* d_out, int out_size, void* d_ws, size_t ws_size,
                              hipStream_t stream) {
    const float* q = (const float*)d_in[0];
    const float* k = (const float*)d_in[1];
    const float* v = (const float*)d_in[2];
    float* out = (float*)d_out;
    float* ws = (float*)d_ws;

    const size_t partial_elems = (size_t)NPB * BH * KVELEM;
    const size_t need = (partial_elems + (size_t)BH * KVELEM) * sizeof(float);

    dim3 blk(256);
    const float* fin_ptr;
    if (ws_size >= need) {
        float* partial = ws;
        float* fin = ws + partial_elems;
        hipLaunchKernelGGL((kv_mfma_kernel<false>), dim3(NPB, BH), blk, 0, stream,
                           k, v, partial);
        hipLaunchKernelGGL(reduce_partials_kernel, dim3((KVELEM + 255) / 256, BH),
                           blk, 0, stream, partial, fin);
        fin_ptr = fin;
    } else {
        float* fin = ws;
        hipMemsetAsync(fin, 0, (size_t)BH * KVELEM * sizeof(float), stream);
        hipLaunchKernelGGL((kv_mfma_kernel<true>), dim3(NPB, BH), blk, 0, stream,
                           k, v, fin);
        fin_ptr = fin;
    }
    hipLaunchKernelGGL(out_kernel, dim3(SEQ / 128, BH), blk, 0, stream,
                       q, fin_ptr, out);
}

// Round 13
// 67.765 us; speedup vs baseline: 1.2413x; 1.0291x over previous
//
#include <hip/hip_runtime.h>

// LinearAttention fp32 [4,16,4096,64]: out = (Q' (K'^T V)) / (Q'.k_sum + eps), X' = elu(X)+1.
// R13 = R12 with the out-store LDS repack made ordering-safe: every LDS write/read
// phase is bracketed by __syncthreads() (R12's barrier-free in-wave repack failed:
// algebra verified by hand, so the failure was compiler/HW ordering, not indexing).
// Pass 1 (kv_mfma): NT loads, single-phase, bf16 MFMA (K=128), 4 blocks/CU.
// Pass 1b (reduce_partials): float4-vectorized fold of NPB partials.
// Pass 2 (out_kernel): Q' bf16 + kv^T bf16 in LDS, 16x MFMA, fp32 denom,
//   acc -> LDS repack (barriered) -> coalesced f32x4 NT stores.

#define EPS_LA 1e-6f

constexpr int BH = 64;
constexpr int SEQ = 4096;
constexpr int DIM = 64;
constexpr int KVELEM = DIM * DIM + DIM;  // 4160
constexpr int NPB = 32;                  // partial blocks per bh
constexpr int SCH = SEQ / NPB;           // 128 s-rows per block

typedef short bf16x8 __attribute__((ext_vector_type(8)));
typedef float f32x4 __attribute__((ext_vector_type(4)));

__device__ __forceinline__ float elu1(float x) {
    return x > 0.f ? x + 1.f : __expf(x);
}
__device__ __forceinline__ f32x4 elu4v(f32x4 v) {
    v[0] = elu1(v[0]); v[1] = elu1(v[1]); v[2] = elu1(v[2]); v[3] = elu1(v[3]);
    return v;
}
__device__ __forceinline__ f32x4 ntld(const float* p) {
    return __builtin_nontemporal_load((const f32x4*)p);
}

// fp32 -> bf16 (RNE; inputs finite)
__device__ __forceinline__ unsigned int f2bf(float x) {
    unsigned int u = __float_as_uint(x);
    return (u + 0x7fffu + ((u >> 16) & 1u)) >> 16;
}
__device__ __forceinline__ unsigned int pack2bf(float lo, float hi) {
    return f2bf(lo) | (f2bf(hi) << 16);
}

// Pass-1 LDS swizzle: dword index into [64 rows][64 dword-cols]
__device__ __forceinline__ int swz(int d, int s2) {
    return d * 64 + (s2 ^ ((((d >> 1) ^ (d >> 2)) & 7) << 2));
}

template<bool ATOMIC>
__global__ __launch_bounds__(256, 4) void kv_mfma_kernel(
    const float* __restrict__ K, const float* __restrict__ V,
    float* __restrict__ dst) {
    const int bh = blockIdx.y;
    const int blk = blockIdx.x;
    const int t = threadIdx.x;
    const int w = t >> 6, l = t & 63;

    __shared__ unsigned int KT[64 * 64];  // 16 KB: K'^T bf16 [d][s-pair] swizzled
    __shared__ unsigned int VT[64 * 64];  // 16 KB
    __shared__ float csumS[4][64];        // 1 KB

    const float* Kb = K + ((size_t)bh * SEQ + (size_t)blk * SCH) * DIM;
    const float* Vb = V + ((size_t)bh * SEQ + (size_t)blk * SCH) * DIM;

    const int c0 = (t & 15) * 4;  // staged col base (d rows c0..c0+3)
    const int pg = t >> 4;        // s-pair group base: pairs pg, pg+16, pg+32, pg+48
    const int lg = l >> 4;        // MFMA k-slice group 0..3
    const int lr = l & 15;        // MFMA row/col within tile

    // ---- issue ALL 16 non-temporal loads ----
    f32x4 kf[8], vf[8];
    #pragma unroll
    for (int i = 0; i < 4; ++i) {
        const int p = pg + 16 * i;
        kf[2 * i]     = ntld(Kb + (size_t)(2 * p) * DIM + c0);
        kf[2 * i + 1] = ntld(Kb + (size_t)(2 * p + 1) * DIM + c0);
    }
    #pragma unroll
    for (int i = 0; i < 4; ++i) {
        const int p = pg + 16 * i;
        vf[2 * i]     = ntld(Vb + (size_t)(2 * p) * DIM + c0);
        vf[2 * i + 1] = ntld(Vb + (size_t)(2 * p + 1) * DIM + c0);
    }

    // ---- elu + pack + transpose into LDS ----
    float cs0 = 0.f, cs1 = 0.f, cs2 = 0.f, cs3 = 0.f;
    #pragma unroll
    for (int i = 0; i < 4; ++i) {
        const int p = pg + 16 * i;
        const f32x4 ka = elu4v(kf[2 * i]);
        const f32x4 kb = elu4v(kf[2 * i + 1]);
        cs0 += ka[0] + kb[0]; cs1 += ka[1] + kb[1];
        cs2 += ka[2] + kb[2]; cs3 += ka[3] + kb[3];
        KT[swz(c0 + 0, p)] = pack2bf(ka[0], kb[0]);
        KT[swz(c0 + 1, p)] = pack2bf(ka[1], kb[1]);
        KT[swz(c0 + 2, p)] = pack2bf(ka[2], kb[2]);
        KT[swz(c0 + 3, p)] = pack2bf(ka[3], kb[3]);
        const f32x4 va = vf[2 * i], vb = vf[2 * i + 1];
        VT[swz(c0 + 0, p)] = pack2bf(va[0], vb[0]);
        VT[swz(c0 + 1, p)] = pack2bf(va[1], vb[1]);
        VT[swz(c0 + 2, p)] = pack2bf(va[2], vb[2]);
        VT[swz(c0 + 3, p)] = pack2bf(va[3], vb[3]);
    }

    // fold column sums across 16-lane groups
    cs0 += __shfl_xor(cs0, 16); cs0 += __shfl_xor(cs0, 32);
    cs1 += __shfl_xor(cs1, 16); cs1 += __shfl_xor(cs1, 32);
    cs2 += __shfl_xor(cs2, 16); cs2 += __shfl_xor(cs2, 32);
    cs3 += __shfl_xor(cs3, 16); cs3 += __shfl_xor(cs3, 32);
    if (l < 16) *(f32x4*)&csumS[w][l * 4] = f32x4{cs0, cs1, cs2, cs3};

    __syncthreads();  // the ONLY barrier

    // ---- MFMA: wave w owns e-cols [16w,16w+16); K=128 (4 steps of 32) ----
    f32x4 acc[4];
    #pragma unroll
    for (int m = 0; m < 4; ++m)
        #pragma unroll
        for (int r = 0; r < 4; ++r) acc[m][r] = 0.f;

    #pragma unroll
    for (int ks = 0; ks < 4; ++ks) {
        const int s2b = ks * 16 + lg * 4;
        const bf16x8 bfrag =
            *reinterpret_cast<const bf16x8*>(&VT[swz(16 * w + lr, s2b)]);
        #pragma unroll
        for (int m = 0; m < 4; ++m) {
            const bf16x8 afrag =
                *reinterpret_cast<const bf16x8*>(&KT[swz(16 * m + lr, s2b)]);
            acc[m] = __builtin_amdgcn_mfma_f32_16x16x32_bf16(afrag, bfrag, acc[m],
                                                             0, 0, 0);
        }
    }

    float* wout = ATOMIC ? dst + (size_t)bh * KVELEM
                         : dst + ((size_t)blk * BH + bh) * KVELEM;

    if (t < 64) {
        const float s = csumS[0][t] + csumS[1][t] + csumS[2][t] + csumS[3][t];
        if (ATOMIC) atomicAdd(&wout[DIM * DIM + t], s);
        else        wout[DIM * DIM + t] = s;
    }

    #pragma unroll
    for (int m = 0; m < 4; ++m) {
        #pragma unroll
        for (int r = 0; r < 4; ++r) {
            const int d = 16 * m + 4 * lg + r;
            const int e = 16 * w + lr;
            if (ATOMIC) atomicAdd(&wout[(size_t)d * DIM + e], acc[m][r]);
            else        wout[(size_t)d * DIM + e] = acc[m][r];
        }
    }
}

__global__ __launch_bounds__(256) void reduce_partials_kernel(
    const float* __restrict__ partial, float* __restrict__ fin) {
    const int bh = blockIdx.y;
    const int j4 = blockIdx.x * 256 + threadIdx.x;  // float4 index, KVELEM/4 = 1040
    if (j4 >= KVELEM / 4) return;
    f32x4 s = {0.f, 0.f, 0.f, 0.f};
    #pragma unroll
    for (int c = 0; c < NPB; ++c)
        s += *(const f32x4*)&partial[((size_t)c * BH + bh) * KVELEM + j4 * 4];
    *(f32x4*)&fin[(size_t)bh * KVELEM + j4 * 4] = s;
}

// Pass 2 (MFMA): block = 256 thr (4 waves); wave wv owns 32 q-rows.
// 2 m-tiles x 4 n-tiles x 2 k-steps = 16 MFMA; fp32 denom via shfl butterfly;
// acc repacked through per-wave LDS (barriered) -> coalesced NT f32x4 stores.
__global__ __launch_bounds__(256) void out_kernel(
    const float* __restrict__ Q, const float* __restrict__ ws,
    float* __restrict__ out) {
    const int bh = blockIdx.y;
    const int rb = blockIdx.x;  // 128-row block
    const int t = threadIdx.x;
    const int wv = t >> 6, l = t & 63;
    const int lr = l & 15, lg = l >> 4;

    __shared__ unsigned int qA[4 * 32 * 32];  // 16 KB: per-wave Q' bf16 [row][d-pair]
    __shared__ unsigned int kvT[64 * 32];     // 8 KB: kv^T bf16 [e][d-pair]
    __shared__ float denomS[128];

    const float* kvp = ws + (size_t)bh * KVELEM;
    const float* Qb = Q + ((size_t)bh * SEQ + (size_t)rb * 128) * DIM;
    float* Ob = out + ((size_t)bh * SEQ + (size_t)rb * 128) * DIM;

    // ---- kvT staging: kv[d][e] -> kvT[e][d-pairs] bf16, swizzled by (e&7) ----
    #pragma unroll
    for (int i = 0; i < 2; ++i) {
        const int p = (t >> 4) + 16 * i;     // d-pair 0..31
        const int e0 = (t & 15) * 4;
        const f32x4 a = *(const f32x4*)(kvp + (size_t)(2 * p) * DIM + e0);
        const f32x4 b = *(const f32x4*)(kvp + (size_t)(2 * p + 1) * DIM + e0);
        #pragma unroll
        for (int j = 0; j < 4; ++j) {
            const int e = e0 + j;
            kvT[e * 32 + (p ^ ((e & 7) << 2))] = pack2bf(a[j], b[j]);
        }
    }

    // ---- q staging (NT): elu, pack bf16, swizzle; fp32 denom partials ----
    const int c0 = lr * 4;
    const f32x4 ks4 = *(const f32x4*)(kvp + DIM * DIM + c0);  // fp32 ksum slice (hot)
    float pd[8];
    #pragma unroll
    for (int it = 0; it < 8; ++it) {
        const int row = it * 4 + lg;          // 0..31 within wave
        const f32x4 qv = elu4v(ntld(Qb + (size_t)(wv * 32 + row) * DIM + c0));
        pd[it] = qv[0] * ks4[0] + qv[1] * ks4[1] + qv[2] * ks4[2] + qv[3] * ks4[3];
        uint2 val;
        val.x = pack2bf(qv[0], qv[1]);
        val.y = pack2bf(qv[2], qv[3]);
        *(uint2*)&qA[wv * 1024 + row * 32 + ((2 * lr) ^ ((row & 7) << 2))] = val;
    }
    // butterfly over the 16-lane (lr) group -> full denom per row
    #pragma unroll
    for (int it = 0; it < 8; ++it) {
        float v = pd[it];
        v += __shfl_xor(v, 1); v += __shfl_xor(v, 2);
        v += __shfl_xor(v, 4); v += __shfl_xor(v, 8);
        if (lr == 0) denomS[wv * 32 + it * 4 + lg] = v + EPS_LA;
    }
    __syncthreads();

    // ---- MFMA: rows 16*mt+lr, cols 16*nt+lr, K=64 in 2 steps ----
    f32x4 acc[2][4];
    #pragma unroll
    for (int mt = 0; mt < 2; ++mt)
        #pragma unroll
        for (int nt = 0; nt < 4; ++nt)
            #pragma unroll
            for (int r = 0; r < 4; ++r) acc[mt][nt][r] = 0.f;

    #pragma unroll
    for (int ks = 0; ks < 2; ++ks) {
        const int kd = 4 * lg + 16 * ks;      // dword base of the lane's k-slice
        const int am = (lr & 7) << 2;
        const bf16x8 a0 = *(const bf16x8*)&qA[wv * 1024 + lr * 32 + (kd ^ am)];
        const bf16x8 a1 = *(const bf16x8*)&qA[wv * 1024 + (16 + lr) * 32 + (kd ^ am)];
        #pragma unroll
        for (int nt = 0; nt < 4; ++nt) {
            const bf16x8 b =
                *(const bf16x8*)&kvT[(16 * nt + lr) * 32 + (kd ^ am)];
            acc[0][nt] = __builtin_amdgcn_mfma_f32_16x16x32_bf16(a0, b, acc[0][nt],
                                                                 0, 0, 0);
            acc[1][nt] = __builtin_amdgcn_mfma_f32_16x16x32_bf16(a1, b, acc[1][nt],
                                                                 0, 0, 0);
        }
    }

    // ---- repack acc through per-wave LDS -> coalesced NT stores.
    // Every write phase and read phase is bracketed by __syncthreads(): R12's
    // barrier-free in-wave version produced wrong results (ordering hazard).
    float* oS = (float*)qA;  // per-wave 1024-float region at wv*1024
    #pragma unroll
    for (int mt = 0; mt < 2; ++mt) {
        __syncthreads();  // qA bf16 reads (mt=0) / prior read-back (mt=1) complete
        #pragma unroll
        for (int r = 0; r < 4; ++r) {
            const int row = 4 * lg + r;  // 0..15
            const float inv = 1.f / denomS[wv * 32 + mt * 16 + row];
            #pragma unroll
            for (int nt = 0; nt < 4; ++nt) {
                const int colp = (16 * nt + lr) ^ (lg << 4);
                oS[wv * 1024 + row * 64 + colp] = acc[mt][nt][r] * inv;
            }
        }
        __syncthreads();  // writes ordered + visible before read-back
        #pragma unroll
        for (int j = 0; j < 4; ++j) {
            const int row = 4 * j + lg;           // 0..15
            const int cb = lr * 4;
            const int colp = cb ^ ((row >> 2) << 4);
            const f32x4 o = *(const f32x4*)&oS[wv * 1024 + row * 64 + colp];
            float* orow = Ob + (size_t)(wv * 32 + mt * 16 + row) * DIM + cb;
            __builtin_nontemporal_store(o, (f32x4*)orow);
        }
    }
}

extern "C" void kernel_launch(void* const* d_in, const int* in_sizes, int n_in,
                              void* d_out, int out_size, void* d_ws, size_t ws_size,
                              hipStream_t stream) {
    const float* q = (const float*)d_in[0];
    const float* k = (const float*)d_in[1];
    const float* v = (const float*)d_in[2];
    float* out = (float*)d_out;
    float* ws = (float*)d_ws;

    const size_t partial_elems = (size_t)NPB * BH * KVELEM;
    const size_t need = (partial_elems + (size_t)BH * KVELEM) * sizeof(float);

    dim3 blk(256);
    const float* fin_ptr;
    if (ws_size >= need) {
        float* partial = ws;
        float* fin = ws + partial_elems;
        hipLaunchKernelGGL((kv_mfma_kernel<false>), dim3(NPB, BH), blk, 0, stream,
                           k, v, partial);
        hipLaunchKernelGGL(reduce_partials_kernel, dim3((KVELEM / 4 + 255) / 256, BH),
                           blk, 0, stream, partial, fin);
        fin_ptr = fin;
    } else {
        float* fin = ws;
        hipMemsetAsync(fin, 0, (size_t)BH * KVELEM * sizeof(float), stream);
        hipLaunchKernelGGL((kv_mfma_kernel<true>), dim3(NPB, BH), blk, 0, stream,
                           k, v, fin);
        fin_ptr = fin;
    }
    hipLaunchKernelGGL(out_kernel, dim3(SEQ / 128, BH), blk, 0, stream,
                       q, fin_ptr, out);
}